// Round 3
// baseline (340.140 us; speedup 1.0000x reference)
//
#include <hip/hip_runtime.h>
#include <math.h>

// ---------------------------------------------------------------------------
// GraphTransformerLayer N=50000, E=640000, D=128, H=8, DH=16  (gfx950)
// Round 14: dispatch-count cut 12 -> 9 kernels + 1 memset:
//   - memset zeroes bn/ready/cursor
//   - k_prep_hist: prep (cast h+weights) UNION edge histogram
//   - k_qkv_scan:  qkv GEMM UNION single-pass chained scan (replaces
//     scanA+scanC; 25 scan blocks lead the grid, agent-scope chain)
// k_attn: 8-edge unroll for MLP; K/V interleaved per-node 512B row (one
// base addr per edge). Q/K/V f16, fdot2 + 3 DPP adds + exp2 (R13 math).
//
// Fragment order for an MxK slab (M=128, K=KB*32):
//   elem index = ((kb*8 + mtile)*64 + lane)*8 + j
//   row = mtile*16 + (lane&15),  col = kb*32 + (lane>>4)*8 + j
// Swapped-operand MFMA: mfma(Wfrag, hfrag) -> C^T: row = m*16+(lane&15),
// cols = w*32+nt*16+quad*4+{0..3} contiguous.
// ---------------------------------------------------------------------------

#define ND128 16384
typedef _Float16 f16;
typedef __attribute__((ext_vector_type(8))) _Float16 h8;
typedef __attribute__((ext_vector_type(4))) _Float16 h4;
typedef __attribute__((ext_vector_type(2))) _Float16 h2;
typedef __attribute__((ext_vector_type(4))) float f4;

__device__ __forceinline__ float fdot2h(h2 a, h2 b) {
#if __has_builtin(__builtin_amdgcn_fdot2)
    return __builtin_amdgcn_fdot2(a, b, 0.f, false);
#else
    return (float)a[0] * (float)b[0] + (float)a[1] * (float)b[1];
#endif
}

__device__ __forceinline__ float fast_exp2(float x) {
#if __has_builtin(__builtin_amdgcn_exp2f)
    return __builtin_amdgcn_exp2f(x);
#else
    return exp2f(x);
#endif
}

// sum across the 8-lane group (lane bits 0..2) via DPP:
// quad_perm[1,0,3,2]=0xB1, quad_perm[2,3,0,1]=0x4E, row_half_mirror=0x141.
template <int CTRL>
__device__ __forceinline__ float dppadd(float x) {
    int t = __builtin_amdgcn_update_dpp(0, __float_as_int(x), CTRL, 0xF, 0xF, false);
    return x + __int_as_float(t);
}
__device__ __forceinline__ float wsum8(float p) {
    p = dppadd<0xB1>(p);
    p = dppadd<0x4E>(p);
    p = dppadd<0x141>(p);
    return p;
}

// --- K1: hist (blocks [0,nhb)) UNION prep (blocks [nhb, nhb+slabs*2)). ----
// cursor/bn/ready zeroed by the preceding memset.
__global__ __launch_bounds__(256) void k_prep_hist(
    const float* __restrict__ h, f16* __restrict__ hb,
    const float* __restrict__ WQ, const float* __restrict__ WK,
    const float* __restrict__ WV, const float* __restrict__ WO,
    const float* __restrict__ W2,
    f16* __restrict__ Wqb, f16* __restrict__ Wkb,
    f16* __restrict__ Wvb, f16* __restrict__ Wob, f16* __restrict__ W2b,
    int* __restrict__ cursor, const int* __restrict__ dst,
    int N, int E, int nhb)
{
    const int tid = threadIdx.x;
    if (blockIdx.x < (unsigned)nhb) {
        int e = blockIdx.x * 256 + tid;
        if (e < E) atomicAdd(&cursor[dst[e]], 1);
        return;
    }
    const int p = blockIdx.x - nhb;
    const int slab = p >> 1, my = p & 1;
#pragma unroll
    for (int it2 = 0; it2 < 4; ++it2) {
        int it = my * 4 + it2;
        int cid = it * 256 + tid;              // 0..2047
        int lane = cid & 63;
        int m = (cid >> 6) & 7;
        int kb = cid >> 9;
        int row = slab * 128 + m * 16 + (lane & 15);
        int col = kb * 32 + (lane >> 4) * 8;
        f16 o8[8];
        if (row < N) {
            const float* pp = h + (size_t)row * 128 + col;
            float4 f0 = *(const float4*)pp;
            float4 f1 = *(const float4*)(pp + 4);
            o8[0] = (f16)f0.x; o8[1] = (f16)f0.y; o8[2] = (f16)f0.z; o8[3] = (f16)f0.w;
            o8[4] = (f16)f1.x; o8[5] = (f16)f1.y; o8[6] = (f16)f1.z; o8[7] = (f16)f1.w;
        } else {
#pragma unroll
            for (int j = 0; j < 8; ++j) o8[j] = (f16)0.f;
        }
        *(h8*)(hb + (size_t)slab * ND128 + (size_t)cid * 8) = *(const h8*)o8;
    }
    if (slab < 6 && my == 1) {
        const float* Wsrc; f16* dstw; int K, base;
        if (slab < 4) {
            Wsrc = slab == 0 ? WQ : slab == 1 ? WK : slab == 2 ? WV : WO;
            dstw = slab == 0 ? Wqb : slab == 1 ? Wkb : slab == 2 ? Wvb : Wob;
            K = 128; base = 0;
        } else {
            Wsrc = W2; dstw = W2b; K = 256; base = (slab - 4) * 2048;
        }
#pragma unroll
        for (int it = 0; it < 8; ++it) {
            int cid = base + it * 256 + tid;
            int lane = cid & 63;
            int kb, nt;
            if (K == 128) { kb = (cid >> 6) & 3; nt = cid >> 8; }
            else          { kb = (cid >> 6) & 7; nt = cid >> 9; }
            int row = nt * 16 + (lane & 15);
            int col = kb * 32 + (lane >> 4) * 8;
            const float* pp = Wsrc + (size_t)row * K + col;
            f16 o8[8];
#pragma unroll
            for (int j = 0; j < 8; ++j) o8[j] = (f16)pp[j];
            *(h8*)(dstw + (size_t)cid * 8) = *(const h8*)o8;
        }
    }
}

// --- K2: chained scan (blocks [0,nsb)) UNION qkv (blocks [nsb, nsb+slabs*6))
// scan: single-pass over counts; publishes inclusive prefix via agent-scope
// release; next block acquires. All 25 scan blocks co-resident -> safe.
// qkv: Q f16 rows; K/V f16 interleaved per-node 512B row in KVb.
__global__ __launch_bounds__(256) void k_qkv_scan(
    const f16* __restrict__ hb, const f16* __restrict__ Wqb,
    const f16* __restrict__ Wkb, const f16* __restrict__ Wvb,
    f16* __restrict__ Qb, f16* __restrict__ KVb,
    int* __restrict__ cursor, int* __restrict__ rowptr,
    int* __restrict__ ready, int N, int nsb)
{
    const int tid = threadIdx.x;
    if (blockIdx.x < (unsigned)nsb) {
        const int b = blockIdx.x;
        int base = b * 2048 + tid * 8;
        int loc[8];
        int s = 0;
#pragma unroll
        for (int j = 0; j < 8; ++j) {
            int idx = base + j;
            loc[j] = (idx < N) ? cursor[idx] : 0;
            s += loc[j];
        }
        __shared__ int part[256];
        part[tid] = s;
        __syncthreads();
        for (int off = 1; off < 256; off <<= 1) {
            int v = (tid >= off) ? part[tid - off] : 0;
            __syncthreads();
            part[tid] += v;
            __syncthreads();
        }
        __shared__ int sboff_sh;
        if (tid == 0) {
            int prev = 0;
            if (b > 0) {
                int r;
                while ((r = __hip_atomic_load(&ready[b - 1], __ATOMIC_ACQUIRE,
                                              __HIP_MEMORY_SCOPE_AGENT)) == 0) {}
                prev = r - 1;
            }
            int btotal = part[255];
            __hip_atomic_store(&ready[b], prev + btotal + 1, __ATOMIC_RELEASE,
                               __HIP_MEMORY_SCOPE_AGENT);
            sboff_sh = prev;
            if (b == nsb - 1) rowptr[N] = prev + btotal;
        }
        __syncthreads();
        int run = sboff_sh + (tid ? part[tid - 1] : 0);
#pragma unroll
        for (int j = 0; j < 8; ++j) {
            int idx = base + j;
            if (idx < N) { rowptr[idx] = run; cursor[idx] = run; run += loc[j]; }
        }
        return;
    }
    const int b2 = blockIdx.x - nsb;
    const int slab = b2 / 6, r6 = b2 % 6;
    const int oidx = r6 >> 1, mh = r6 & 1;
    const int w = tid >> 6, lane = tid & 63;
    const f16* __restrict__ Wb = oidx == 0 ? Wqb : oidx == 1 ? Wkb : Wvb;
    const f16* A = hb + (size_t)slab * ND128;

    h8 bfr[2][4];
#pragma unroll
    for (int nt = 0; nt < 2; ++nt)
#pragma unroll
        for (int kb = 0; kb < 4; ++kb)
            bfr[nt][kb] = *(const h8*)(Wb + (size_t)(((2 * w + nt) * 4 + kb) * 64 + lane) * 8);

    f4 acc[4][2];
    f4 zero = {0.f, 0.f, 0.f, 0.f};
#pragma unroll
    for (int m = 0; m < 4; ++m) { acc[m][0] = zero; acc[m][1] = zero; }

#pragma unroll
    for (int m = 0; m < 4; ++m) {
        int mg = mh * 4 + m;
#pragma unroll
        for (int kb = 0; kb < 4; ++kb) {
            h8 a = *(const h8*)(A + (size_t)((kb * 8 + mg) * 64 + lane) * 8);
            acc[m][0] = __builtin_amdgcn_mfma_f32_16x16x32_f16(bfr[0][kb], a, acc[m][0], 0, 0, 0);
            acc[m][1] = __builtin_amdgcn_mfma_f32_16x16x32_f16(bfr[1][kb], a, acc[m][1], 0, 0, 0);
        }
    }

    const int rl = lane & 15, quad = lane >> 4;
#pragma unroll
    for (int m = 0; m < 4; ++m) {
        int gr = slab * 128 + (mh * 4 + m) * 16 + rl;
        if (gr < N) {
#pragma unroll
            for (int nt = 0; nt < 2; ++nt) {
                h4 o;
                o[0] = (f16)acc[m][nt][0]; o[1] = (f16)acc[m][nt][1];
                o[2] = (f16)acc[m][nt][2]; o[3] = (f16)acc[m][nt][3];
                int col = w * 32 + nt * 16 + quad * 4;
                if (oidx == 0) {
                    *(h4*)(Qb + (size_t)gr * 128 + col) = o;
                } else {
                    *(h4*)(KVb + (size_t)gr * 256 + (oidx == 1 ? col : 128 + col)) = o;
                }
            }
        }
    }
}

// --- K3: scatter edges into CSR -------------------------------------------
__global__ __launch_bounds__(256) void k_scatter(
    const int* __restrict__ src, const int* __restrict__ dst,
    int* __restrict__ cursor, int* __restrict__ csr_src, int E)
{
    int e = blockIdx.x * 256 + threadIdx.x;
    if (e < E) {
        int pos = atomicAdd(&cursor[dst[e]], 1);
        csr_src[pos] = src[e];
    }
}

// --- attention: one wave per node, lane owns channels (2l, 2l+1). ----------
// KV interleaved row (K 256B | V 256B). 8-edge unroll main loop.
__global__ __launch_bounds__(256) void k_attn(
    const f16* __restrict__ Qb, const f16* __restrict__ KVb,
    const int* __restrict__ rowptr, const int* __restrict__ csr_src,
    f16* __restrict__ attnf, int N)
{
    const int node = blockIdx.x * 4 + (threadIdx.x >> 6);
    const int lane = threadIdx.x & 63;
    if (node >= N) return;
    const int beg = rowptr[node], end = rowptr[node + 1];

    h2 qs;
    {
        h2 q2 = ((const h2*)(Qb + (size_t)node * 128))[lane];
        const float SCL = 0.25f * 1.44269504f;
        qs[0] = (f16)((float)q2[0] * SCL);
        qs[1] = (f16)((float)q2[1] * SCL);
    }
    const float CLP = 5.f * 1.44269504f;

    const h2* __restrict__ KV2 = (const h2*)KVb;   // row stride 128 h2

    h2 accA, accB;
    accA[0] = (f16)0.f; accA[1] = (f16)0.f;
    accB[0] = (f16)0.f; accB[1] = (f16)0.f;
    float z = 0.f;

    int i = beg;
    for (; i + 7 < end; i += 8) {
        int s[8];
#pragma unroll
        for (int u = 0; u < 8; ++u) s[u] = csr_src[i + u];
        h2 kk[8], vv[8];
#pragma unroll
        for (int u = 0; u < 8; ++u) {
            const h2* row = KV2 + (size_t)s[u] * 128;
            kk[u] = row[lane];
            vv[u] = row[64 + lane];
        }
        float sc[8];
#pragma unroll
        for (int u = 0; u < 8; ++u) {
            float p = wsum8(fdot2h(qs, kk[u]));
            sc[u] = fast_exp2(fminf(fmaxf(p, -CLP), CLP));
        }
#pragma unroll
        for (int u = 0; u < 8; ++u) z += sc[u];
#pragma unroll
        for (int u = 0; u < 8; ++u) {
            h2 c; c[0] = (f16)sc[u]; c[1] = (f16)sc[u];
            if (u & 1) accB += c * vv[u]; else accA += c * vv[u];
        }
    }
    if (i + 3 < end) {
        int s[4];
#pragma unroll
        for (int u = 0; u < 4; ++u) s[u] = csr_src[i + u];
        h2 kk[4], vv[4];
#pragma unroll
        for (int u = 0; u < 4; ++u) {
            const h2* row = KV2 + (size_t)s[u] * 128;
            kk[u] = row[lane];
            vv[u] = row[64 + lane];
        }
#pragma unroll
        for (int u = 0; u < 4; ++u) {
            float p = wsum8(fdot2h(qs, kk[u]));
            float scu = fast_exp2(fminf(fmaxf(p, -CLP), CLP));
            z += scu;
            h2 c; c[0] = (f16)scu; c[1] = (f16)scu;
            if (u & 1) accB += c * vv[u]; else accA += c * vv[u];
        }
        i += 4;
    }
    for (; i < end; ++i) {
        int s0 = csr_src[i];
        const h2* row = KV2 + (size_t)s0 * 128;
        h2 k0 = row[lane];
        h2 v0 = row[64 + lane];
        float p0 = wsum8(fdot2h(qs, k0));
        float sc0 = fast_exp2(fminf(fmaxf(p0, -CLP), CLP));
        z += sc0;
        h2 c0; c0[0] = (f16)sc0; c0[1] = (f16)sc0;
        accA += c0 * v0;
    }

    float inv = 1.f / z;
    float ax = ((float)accA[0] + (float)accB[0]) * inv;
    float ay = ((float)accA[1] + (float)accB[1]) * inv;
    h2 o2;
    o2[0] = (f16)ax; o2[1] = (f16)ay;
    int slab = node >> 7, m = (node >> 4) & 7, lr = node & 15;
    int kb = lane >> 4, quad2 = (lane & 15) >> 2, j = (lane & 3) * 2;
    *(h2*)(attnf + (size_t)slab * ND128 +
           (size_t)(((kb * 8 + m) * 64 + lr + 16 * quad2) * 8 + j)) = o2;
}

// --- O-proj: t1 = attn @ WO^T + h + bO -> f16 frag t1b; BN1 sums. ----------
__global__ __launch_bounds__(256) void k_oproj(
    const f16* __restrict__ attnf, const f16* __restrict__ Wob,
    const float* __restrict__ h, const float* __restrict__ bO,
    f16* __restrict__ t1b, float* __restrict__ bn, int N)
{
    __shared__ float csum[128], csq[128];
    const int tid = threadIdx.x, slab = blockIdx.x, mh = blockIdx.y;
    const int w = tid >> 6, lane = tid & 63;
    if (tid < 128) { csum[tid] = 0.f; csq[tid] = 0.f; }
    __syncthreads();
    const f16* A = attnf + (size_t)slab * ND128;

    h8 bfr[2][4];
#pragma unroll
    for (int nt = 0; nt < 2; ++nt)
#pragma unroll
        for (int kb = 0; kb < 4; ++kb)
            bfr[nt][kb] = *(const h8*)(Wob + (size_t)(((2 * w + nt) * 4 + kb) * 64 + lane) * 8);

    f4 acc[4][2];
    f4 zero = {0.f, 0.f, 0.f, 0.f};
#pragma unroll
    for (int m = 0; m < 4; ++m) { acc[m][0] = zero; acc[m][1] = zero; }
#pragma unroll
    for (int m = 0; m < 4; ++m) {
        int mg = mh * 4 + m;
#pragma unroll
        for (int kb = 0; kb < 4; ++kb) {
            h8 a = *(const h8*)(A + (size_t)((kb * 8 + mg) * 64 + lane) * 8);
            acc[m][0] = __builtin_amdgcn_mfma_f32_16x16x32_f16(bfr[0][kb], a, acc[m][0], 0, 0, 0);
            acc[m][1] = __builtin_amdgcn_mfma_f32_16x16x32_f16(bfr[1][kb], a, acc[m][1], 0, 0, 0);
        }
    }

    const int rl = lane & 15, quad = lane >> 4;
    float4 bo[2];
#pragma unroll
    for (int nt = 0; nt < 2; ++nt)
        bo[nt] = *(const float4*)(bO + w * 32 + nt * 16 + quad * 4);
    float pcs[2][4], pcq[2][4];
#pragma unroll
    for (int nt = 0; nt < 2; ++nt)
#pragma unroll
        for (int r = 0; r < 4; ++r) { pcs[nt][r] = 0.f; pcq[nt][r] = 0.f; }

#pragma unroll
    for (int m = 0; m < 4; ++m) {
        int mg = mh * 4 + m;
        int gr = slab * 128 + mg * 16 + rl;
        if (gr < N) {
#pragma unroll
            for (int nt = 0; nt < 2; ++nt) {
                int col0 = w * 32 + nt * 16 + quad * 4;
                float4 hv = *(const float4*)(h + (size_t)gr * 128 + col0);
                float v0 = acc[m][nt][0] + hv.x + bo[nt].x;
                float v1 = acc[m][nt][1] + hv.y + bo[nt].y;
                float v2 = acc[m][nt][2] + hv.z + bo[nt].z;
                float v3 = acc[m][nt][3] + hv.w + bo[nt].w;
                h4 o; o[0] = (f16)v0; o[1] = (f16)v1; o[2] = (f16)v2; o[3] = (f16)v3;
                *(h4*)(t1b + (size_t)slab * ND128 +
                       (size_t)(((w * 8 + mg) * 64 + (nt * 2 + (quad >> 1)) * 16 + rl) * 8 +
                                (quad & 1) * 4)) = o;
                pcs[nt][0] += v0; pcq[nt][0] += v0 * v0;
                pcs[nt][1] += v1; pcq[nt][1] += v1 * v1;
                pcs[nt][2] += v2; pcq[nt][2] += v2 * v2;
                pcs[nt][3] += v3; pcq[nt][3] += v3 * v3;
            }
        }
    }
#pragma unroll
    for (int nt = 0; nt < 2; ++nt)
#pragma unroll
        for (int r = 0; r < 4; ++r) {
            float s = pcs[nt][r], q = pcq[nt][r];
            s += __shfl_xor(s, 8, 16); q += __shfl_xor(q, 8, 16);
            s += __shfl_xor(s, 4, 16); q += __shfl_xor(q, 4, 16);
            s += __shfl_xor(s, 2, 16); q += __shfl_xor(q, 2, 16);
            s += __shfl_xor(s, 1, 16); q += __shfl_xor(q, 1, 16);
            if (rl == 0) {
                int cl = w * 32 + nt * 16 + quad * 4 + r;
                atomicAdd(&csum[cl], s);
                atomicAdd(&csq[cl], q);
            }
        }
    __syncthreads();
    if (tid < 128) {
        atomicAdd(bn + tid, csum[tid]);
        atomicAdd(bn + 128 + tid, csq[tid]);
    }
}

// --- fold BN1 into W1/bias. 256 blocks (one per W1 row). -------------------
__global__ __launch_bounds__(128) void k_fold1(
    const float* __restrict__ bn, const float* __restrict__ g1,
    const float* __restrict__ bb1, const float* __restrict__ W1,
    const float* __restrict__ b1, f16* __restrict__ W1b,
    float* __restrict__ badj, float* __restrict__ sfold,
    float* __restrict__ bfold, int N)
{
    const int o = blockIdx.x, i = threadIdx.x;
    float invN = 1.f / (float)N;
    float mu = bn[i] * invN;
    float var = bn[128 + i] * invN - mu * mu;
    float s = g1[i] * rsqrtf(var + 1e-5f);
    float bb = bb1[i] - mu * s;
    if (o == 0) { sfold[i] = s; bfold[i] = bb; }
    float wv = W1[(size_t)o * 128 + i];
    __shared__ float red[128];
    red[i] = wv * bb;
    const int nt = o >> 4, lanelow = o & 15;
    const int kb = i >> 5, quad = (i >> 3) & 3, j = i & 7;
    W1b[(size_t)(((nt * 4 + kb) * 64 + lanelow + 16 * quad) * 8 + j)] = (f16)(wv * s);
    __syncthreads();
#pragma unroll
    for (int off = 64; off; off >>= 1) {
        if (i < off) red[i] += red[i + off];
        __syncthreads();
    }
    if (i == 0) badj[o] = b1[o] + red[0];
}

// --- FFN1: u = relu(t1b @ W1s^T + badj), f16 frag order (K=256 layout). ----
__global__ __launch_bounds__(256) void k_ffn1(
    const f16* __restrict__ t1b, const f16* __restrict__ W1b,
    const float* __restrict__ badj, f16* __restrict__ ub, int N)
{
    const int slab = blockIdx.x, ch = blockIdx.y, mh = blockIdx.z;
    const int w = threadIdx.x >> 6, lane = threadIdx.x & 63;
    const f16* A = t1b + (size_t)slab * ND128;

    h8 bfr[2][4];
#pragma unroll
    for (int nt = 0; nt < 2; ++nt)
#pragma unroll
        for (int kb = 0; kb < 4; ++kb) {
            int ntg = ch * 8 + 2 * w + nt;
            bfr[nt][kb] = *(const h8*)(W1b + (size_t)((ntg * 4 + kb) * 64 + lane) * 8);
        }

    f4 acc[4][2];
    f4 zero = {0.f, 0.f, 0.f, 0.f};
#pragma unroll
    for (int m = 0; m < 4; ++m) { acc[m][0] = zero; acc[m][1] = zero; }
#pragma unroll
    for (int m = 0; m < 4; ++m) {
        int mg = mh * 4 + m;
#pragma unroll
        for (int kb = 0; kb < 4; ++kb) {
            h8 a = *(const h8*)(A + (size_t)((kb * 8 + mg) * 64 + lane) * 8);
            acc[m][0] = __builtin_amdgcn_mfma_f32_16x16x32_f16(bfr[0][kb], a, acc[m][0], 0, 0, 0);
            acc[m][1] = __builtin_amdgcn_mfma_f32_16x16x32_f16(bfr[1][kb], a, acc[m][1], 0, 0, 0);
        }
    }

    const int rl = lane & 15, quad = lane >> 4;
    const int kbu = ch * 4 + w;
    float4 ba[2];
#pragma unroll
    for (int nt = 0; nt < 2; ++nt)
        ba[nt] = *(const float4*)(badj + ch * 128 + w * 32 + nt * 16 + quad * 4);
#pragma unroll
    for (int m = 0; m < 4; ++m) {
        int mg = mh * 4 + m;
        int gr = slab * 128 + mg * 16 + rl;
        if (gr < N) {
#pragma unroll
            for (int nt = 0; nt < 2; ++nt) {
                h4 o;
                o[0] = (f16)fmaxf(acc[m][nt][0] + ba[nt].x, 0.f);
                o[1] = (f16)fmaxf(acc[m][nt][1] + ba[nt].y, 0.f);
                o[2] = (f16)fmaxf(acc[m][nt][2] + ba[nt].z, 0.f);
                o[3] = (f16)fmaxf(acc[m][nt][3] + ba[nt].w, 0.f);
                *(h4*)(ub + (size_t)slab * 32768 +
                       (size_t)(((kbu * 8 + mg) * 64 + (nt * 2 + (quad >> 1)) * 16 + rl) * 8 +
                                (quad & 1) * 4)) = o;
            }
        }
    }
}

// --- FFN2: t2 = (s1*t1 + b1v + b2) + u @ W2^T; fp32 out; BN2 sums. ---------
__global__ __launch_bounds__(256) void k_ffn2(
    const f16* __restrict__ ub, const f16* __restrict__ W2b,
    const f16* __restrict__ t1b,
    const float* __restrict__ sfold, const float* __restrict__ bfold,
    const float* __restrict__ b2, float* __restrict__ out,
    float* __restrict__ bn, int N)
{
    __shared__ float csum[128], csq[128], sS[128], sB[128];
    const int tid = threadIdx.x, slab = blockIdx.x, mh = blockIdx.y;
    const int w = tid >> 6, lane = tid & 63;
    if (tid < 128) {
        csum[tid] = 0.f; csq[tid] = 0.f;
        sS[tid] = sfold[tid]; sB[tid] = bfold[tid] + b2[tid];
    }
    __syncthreads();
    const f16* A = ub + (size_t)slab * 32768;
    const f16* T1 = t1b + (size_t)slab * ND128;

    h8 bfr[2][8];
#pragma unroll
    for (int nt = 0; nt < 2; ++nt)
#pragma unroll
        for (int kb = 0; kb < 8; ++kb)
            bfr[nt][kb] = *(const h8*)(W2b + (size_t)(((2 * w + nt) * 8 + kb) * 64 + lane) * 8);

    f4 acc[4][2];
    f4 zero = {0.f, 0.f, 0.f, 0.f};
#pragma unroll
    for (int m = 0; m < 4; ++m) { acc[m][0] = zero; acc[m][1] = zero; }
#pragma unroll
    for (int m = 0; m < 4; ++m) {
        int mg = mh * 4 + m;
#pragma unroll
        for (int kb = 0; kb < 8; ++kb) {
            h8 a = *(const h8*)(A + (size_t)((kb * 8 + mg) * 64 + lane) * 8);
            acc[m][0] = __builtin_amdgcn_mfma_f32_16x16x32_f16(bfr[0][kb], a, acc[m][0], 0, 0, 0);
            acc[m][1] = __builtin_amdgcn_mfma_f32_16x16x32_f16(bfr[1][kb], a, acc[m][1], 0, 0, 0);
        }
    }

    const int rl = lane & 15, quad = lane >> 4;
    float pcs[2][4], pcq[2][4];
#pragma unroll
    for (int nt = 0; nt < 2; ++nt)
#pragma unroll
        for (int r = 0; r < 4; ++r) { pcs[nt][r] = 0.f; pcq[nt][r] = 0.f; }

#pragma unroll
    for (int m = 0; m < 4; ++m) {
        int mg = mh * 4 + m;
        int gr = slab * 128 + mg * 16 + rl;
        if (gr < N) {
#pragma unroll
            for (int nt = 0; nt < 2; ++nt) {
                int col0 = w * 32 + nt * 16 + quad * 4;
                h4 t1v = *(const h4*)(T1 +
                    (size_t)(((w * 8 + mg) * 64 + (nt * 2 + (quad >> 1)) * 16 + rl) * 8 +
                             (quad & 1) * 4));
                float4 ss = *(const float4*)&sS[col0];
                float4 sb = *(const float4*)&sB[col0];
                float4 o;
                o.x = acc[m][nt][0] + fmaf(ss.x, (float)t1v[0], sb.x);
                o.y = acc[m][nt][1] + fmaf(ss.y, (float)t1v[1], sb.y);
                o.z = acc[m][nt][2] + fmaf(ss.z, (float)t1v[2], sb.z);
                o.w = acc[m][nt][3] + fmaf(ss.w, (float)t1v[3], sb.w);
                *(float4*)(out + (size_t)gr * 128 + col0) = o;
                pcs[nt][0] += o.x; pcq[nt][0] += o.x * o.x;
                pcs[nt][1] += o.y; pcq[nt][1] += o.y * o.y;
                pcs[nt][2] += o.z; pcq[nt][2] += o.z * o.z;
                pcs[nt][3] += o.w; pcq[nt][3] += o.w * o.w;
            }
        }
    }
#pragma unroll
    for (int nt = 0; nt < 2; ++nt)
#pragma unroll
        for (int r = 0; r < 4; ++r) {
            float s = pcs[nt][r], q = pcq[nt][r];
            s += __shfl_xor(s, 8, 16); q += __shfl_xor(q, 8, 16);
            s += __shfl_xor(s, 4, 16); q += __shfl_xor(q, 4, 16);
            s += __shfl_xor(s, 2, 16); q += __shfl_xor(q, 2, 16);
            s += __shfl_xor(s, 1, 16); q += __shfl_xor(q, 1, 16);
            if (rl == 0) {
                int cl = w * 32 + nt * 16 + quad * 4 + r;
                atomicAdd(&csum[cl], s);
                atomicAdd(&csq[cl], q);
            }
        }
    __syncthreads();
    if (tid < 128) {
        atomicAdd(bn + 256 + tid, csum[tid]);
        atomicAdd(bn + 384 + tid, csq[tid]);
    }
}

// --- BN2 normalize in place ------------------------------------------------
__global__ __launch_bounds__(256) void k_bn2(
    float* __restrict__ out, const float* __restrict__ bn,
    const float* __restrict__ g2, const float* __restrict__ bb2, int N)
{
    __shared__ float sS[128], sB[128];
    const int tid = threadIdx.x;
    if (tid < 128) {
        float invN = 1.f / (float)N;
        float mu = bn[256 + tid] * invN;
        float var = bn[384 + tid] * invN - mu * mu;
        float scl = g2[tid] * rsqrtf(var + 1e-5f);
        sS[tid] = scl;
        sB[tid] = bb2[tid] - mu * scl;
    }
    __syncthreads();
    size_t idx = (size_t)blockIdx.x * 256 + tid;
    size_t total = (size_t)N * 32;
    if (idx < total) {
        int c0 = (int)((idx * 4) & 127);
        float4 v = *(const float4*)(out + idx * 4);
        v.x = fmaf(v.x, sS[c0 + 0], sB[c0 + 0]);
        v.y = fmaf(v.y, sS[c0 + 1], sB[c0 + 1]);
        v.z = fmaf(v.z, sS[c0 + 2], sB[c0 + 2]);
        v.w = fmaf(v.w, sS[c0 + 3], sB[c0 + 3]);
        *(float4*)(out + idx * 4) = v;
    }
}

extern "C" void kernel_launch(void* const* d_in, const int* in_sizes, int n_in,
                              void* d_out, int out_size, void* d_ws, size_t ws_size,
                              hipStream_t stream)
{
    const float* h   = (const float*)d_in[0];
    const int*   src = (const int*)d_in[1];
    const int*   dst = (const int*)d_in[2];
    const float* WQ  = (const float*)d_in[3];
    const float* WK  = (const float*)d_in[4];
    const float* WV  = (const float*)d_in[5];
    const float* WO  = (const float*)d_in[6];
    const float* bO  = (const float*)d_in[7];
    const float* W1  = (const float*)d_in[8];
    const float* b1  = (const float*)d_in[9];
    const float* W2  = (const float*)d_in[10];
    const float* b2  = (const float*)d_in[11];
    const float* g1  = (const float*)d_in[12];
    const float* bb1 = (const float*)d_in[13];
    const float* g2  = (const float*)d_in[14];
    const float* bb2 = (const float*)d_in[15];
    float* out = (float*)d_out;

    int N = in_sizes[0] / 128;
    int E = in_sizes[1];
    const int slabs = (N + 127) / 128;
    const int nsb = (N + 2047) / 2048;         // scan blocks (~25)
    const int nhb = (E + 255) / 256;           // edge blocks (~2500)
    const size_t B1 = (size_t)slabs * 32768;   // bytes of one f16 N_pad x 128 buffer

    char* Wp = (char*)d_ws;
    f16* hb  = (f16*)Wp;                       // becomes attnf after attn
    f16* Qb  = (f16*)(Wp + B1);                // B1
    f16* KVb = (f16*)(Wp + 2 * B1);            // 2*B1 (f16 K|V interleaved rows)
    f16* ub  = (f16*)(Wp + B1);                // 2*B1, overlays Qb + KVb.K after attn
    f16* t1b = (f16*)(Wp + 3 * B1);            // B1, overlays KVb.V tail (dead after attn)
    const size_t base = 4 * B1;
    f16* Wqb = (f16*)(Wp + base);
    f16* Wkb = (f16*)(Wp + base + 32768);
    f16* Wvb = (f16*)(Wp + base + 65536);
    f16* Wob = (f16*)(Wp + base + 98304);
    f16* W1b = (f16*)(Wp + base + 131072);
    f16* W2b = (f16*)(Wp + base + 196608);
    float* badj  = (float*)(Wp + base + 262144);
    float* sfold = (float*)(Wp + base + 263168);
    float* bfold = (float*)(Wp + base + 263680);
    float* bn    = (float*)(Wp + base + 264192);     // 512 floats (memset)
    int* ready   = (int*)(Wp + base + 266240);       // 64 ints (memset)
    int* cursor  = (int*)(Wp + base + 266496);       // N ints (memset)
    int* rowptr  = (int*)(Wp + base + 266496 + (size_t)N * 4);
    int* csr     = (int*)(Wp + base + 266496 + (size_t)N * 8 + 8);

    // zero bn(2048B) + ready(256B) + cursor(N*4) in one memset
    hipMemsetAsync(Wp + base + 264192, 0, 2304 + (size_t)N * 4, stream);
    k_prep_hist<<<nhb + slabs * 2, 256, 0, stream>>>(
        h, hb, WQ, WK, WV, WO, W2, Wqb, Wkb, Wvb, Wob, W2b, cursor, dst, N, E, nhb);
    k_qkv_scan<<<nsb + slabs * 6, 256, 0, stream>>>(
        hb, Wqb, Wkb, Wvb, Qb, KVb, cursor, rowptr, ready, N, nsb);
    k_scatter<<<nhb, 256, 0, stream>>>(src, dst, cursor, csr, E);
    k_attn<<<(N + 3) / 4, 256, 0, stream>>>(Qb, KVb, rowptr, csr, hb, N);
    k_oproj<<<dim3(slabs, 2), 256, 0, stream>>>(hb, Wob, h, bO, t1b, bn, N);
    k_fold1<<<256, 128, 0, stream>>>(bn, g1, bb1, W1, b1, W1b, badj, sfold, bfold, N);
    k_ffn1<<<dim3(slabs, 2, 2), 256, 0, stream>>>(t1b, W1b, badj, ub, N);
    k_ffn2<<<dim3(slabs, 2), 256, 0, stream>>>(ub, W2b, t1b, sfold, bfold, b2, out, bn, N);
    k_bn2<<<(int)(((size_t)N * 32 + 255) / 256), 256, 0, stream>>>(out, bn, g2, bb2, N);
}